// Round 6
// baseline (5982.273 us; speedup 1.0000x reference)
//
#include <hip/hip_runtime.h>
#include <hip/hip_fp16.h>
#include <math.h>

#define T_LEN 2500
#define BATCH 64
#define CH    12
#define HID   64
#define G4    256   // 4*H
#define D2    128   // 2*H
#define NROW  (T_LEN*BATCH)

__device__ __forceinline__ float rcp_(float x){ return __builtin_amdgcn_rcpf(x); }
__device__ __forceinline__ float sig_(float x){ return rcp_(1.f + __expf(-x)); }

__device__ __forceinline__ float ldv(const float* p){ return *p; }
__device__ __forceinline__ float ldv(const __half* p){ return __half2float(*p); }
__device__ __forceinline__ void stv(float* p, float v){ *p = v; }
__device__ __forceinline__ void stv(__half* p, float v){ *p = __float2half(v); }

// quad_perm DPP move (full-rate VALU)
template<int CTRL>
__device__ __forceinline__ float qperm(float v) {
  return __int_as_float(__builtin_amdgcn_mov_dpp(__float_as_int(v), CTRL, 0xf, 0xf, true));
}

// Raw barrier: LDS-ordering only; does NOT drain vmcnt (global prefetch stays in flight).
__device__ __forceinline__ void bar_lds() {
  asm volatile("s_waitcnt lgkmcnt(0)" ::: "memory");
  __builtin_amdgcn_s_barrier();
  __builtin_amdgcn_sched_barrier(0);
}

// dot over K=64 from LDS-broadcast h, 4 independent chains.
__device__ __forceinline__ float dot64(const float* hr, const float* w, float seed) {
  float s0 = seed, s1 = 0.f, s2 = 0.f, s3 = 0.f;
#pragma unroll
  for (int k = 0; k < HID; k += 16) {
    const float4 a0 = *reinterpret_cast<const float4*>(&hr[k]);
    const float4 a1 = *reinterpret_cast<const float4*>(&hr[k + 4]);
    const float4 a2 = *reinterpret_cast<const float4*>(&hr[k + 8]);
    const float4 a3 = *reinterpret_cast<const float4*>(&hr[k + 12]);
    s0 = fmaf(a0.x, w[k], s0);      s0 = fmaf(a0.y, w[k + 1], s0);
    s0 = fmaf(a0.z, w[k + 2], s0);  s0 = fmaf(a0.w, w[k + 3], s0);
    s1 = fmaf(a1.x, w[k + 4], s1);  s1 = fmaf(a1.y, w[k + 5], s1);
    s1 = fmaf(a1.z, w[k + 6], s1);  s1 = fmaf(a1.w, w[k + 7], s1);
    s2 = fmaf(a2.x, w[k + 8], s2);  s2 = fmaf(a2.y, w[k + 9], s2);
    s2 = fmaf(a2.z, w[k + 10], s2); s2 = fmaf(a2.w, w[k + 11], s2);
    s3 = fmaf(a3.x, w[k + 12], s3); s3 = fmaf(a3.y, w[k + 13], s3);
    s3 = fmaf(a3.z, w[k + 14], s3); s3 = fmaf(a3.w, w[k + 15], s3);
  }
  return (s0 + s1) + (s2 + s3);
}

// Per-lane gate nonlinearity (gi==2 -> tanh, else sigmoid), then quad-gather
// into leader (gi==0) and cell update. All lanes compute; only leader's valid.
__device__ __forceinline__ float cell_update(float v, int gi, float& c) {
  const float z = (gi == 2) ? (v + v) : v;
  const float y = sig_(z);
  const float act = (gi == 2) ? fmaf(2.f, y, -1.f) : y;
  const float t1 = qperm<0xB1>(act);   // lane^1
  const float t2 = qperm<0x4E>(act);   // lane^2
  const float t3 = qperm<0x4E>(t1);    // lane^3
  // leader: act=i, t1=f, t2=g, t3=o
  c = fmaf(t1, c, act * t2);
  const float y2 = sig_(c + c);
  const float th = fmaf(2.f, y2, -1.f);   // tanh(c)
  return t3 * th;
}

// ---------------------------------------------------------------------------
// Fold input projection into layer-0 input weights.
// ---------------------------------------------------------------------------
__global__ void k_prep0(const float* __restrict__ Wp, const float* __restrict__ bp,
                        const float* __restrict__ w_ih0,
                        const float* __restrict__ b_ih0, const float* __restrict__ b_hh0,
                        float* __restrict__ w0p, float* __restrict__ b0p) {
  int tid = blockIdx.x * blockDim.x + threadIdx.x;
  if (tid >= 2 * G4) return;
  const float* wih = w_ih0 + (size_t)tid * HID;
  float bb = b_ih0[tid] + b_hh0[tid];
  for (int j = 0; j < HID; ++j) bb += wih[j] * bp[j];
  b0p[tid] = bb;
  for (int c = 0; c < CH; ++c) {
    float s = 0.f;
    for (int j = 0; j < HID; ++j) s += wih[j] * Wp[j * CH + c];
    w0p[(size_t)tid * CH + c] = s;
  }
}

// ---------------------------------------------------------------------------
// Layer-0 recurrence. WG per (dir,b), 256 thr = 4 waves.
// lane -> (unit j = w*16 + l/4, gate gi = l&3); 64 weight VGPRs per lane.
// __launch_bounds__(256,1): only 128 WGs exist (<=1/CU) -- let the allocator
// use a big VGPR budget so the Whh row stays IN REGISTERS (round-5 profile
// showed VGPR_Count=64 => compiler re-loaded weights every step, 1555 cy/step).
// ---------------------------------------------------------------------------
template<typename ST>
__global__ __launch_bounds__(256, 1) void k_recur0(const float* __restrict__ x,
                                                   const float* __restrict__ w0p,
                                                   const float* __restrict__ b0p,
                                                   const float* __restrict__ whh,
                                                   ST* __restrict__ seq) {
  const int wg = blockIdx.x, dir = wg >> 6, b = wg & 63;
  const int w4 = threadIdx.x >> 6, l = threadIdx.x & 63;
  const int gi = l & 3, j = w4 * 16 + (l >> 2);
  const int row = dir * G4 + gi * HID + j;

  float w[HID];
  {
    const float* W = whh + (size_t)row * HID;
#pragma unroll
    for (int k = 0; k < HID; ++k) w[k] = W[k];
  }
  float w0[CH];
  {
    const float* P = w0p + (size_t)row * CH;
#pragma unroll
    for (int c = 0; c < CH; ++c) w0[c] = P[c];
  }
  const float bb = b0p[row];

  __shared__ __align__(16) float h_lds[2][HID];
  if (threadIdx.x < HID) { h_lds[0][threadIdx.x] = 0.f; }
  float c = 0.f;

  int t = dir ? (T_LEN - 1) : 0;
  const int dt = dir ? -1 : 1;
  const float* xb = x + (size_t)b * CH * T_LEN;

  float xc[CH], xn[CH];
#pragma unroll
  for (int cc = 0; cc < CH; ++cc) xc[cc] = xb[(size_t)cc * T_LEN + t];
  {
    const int t1 = t + dt;
#pragma unroll
    for (int cc = 0; cc < CH; ++cc) xn[cc] = xb[(size_t)cc * T_LEN + t1];
  }
  bar_lds();

  int par = 0;
#pragma unroll 2
  for (int it = 0; it < T_LEN; ++it) {
    // seed = bias + input projection (uses xc = x[t])
    float p0 = bb, p1 = 0.f, p2 = 0.f;
#pragma unroll
    for (int cc = 0; cc < 4; ++cc)  p0 = fmaf(xc[cc], w0[cc], p0);
#pragma unroll
    for (int cc = 4; cc < 8; ++cc)  p1 = fmaf(xc[cc], w0[cc], p1);
#pragma unroll
    for (int cc = 8; cc < 12; ++cc) p2 = fmaf(xc[cc], w0[cc], p2);

    // shift prefetch and issue loads for t+2 (overlaps the dot below)
#pragma unroll
    for (int cc = 0; cc < CH; ++cc) xc[cc] = xn[cc];
    {
      int t2 = t + 2 * dt;
      t2 = (t2 < 0) ? 0 : ((t2 > T_LEN - 1) ? (T_LEN - 1) : t2);
#pragma unroll
      for (int cc = 0; cc < CH; ++cc) xn[cc] = xb[(size_t)cc * T_LEN + t2];
    }

    const float pre = dot64(&h_lds[par][0], w, (p0 + p1) + p2);
    const float hv = cell_update(pre, gi, c);

    if ((l & 3) == 0) {
      h_lds[par ^ 1][j] = hv;
      stv(&seq[((size_t)t * BATCH + b) * D2 + dir * HID + j], hv);
    }
    bar_lds();
    par ^= 1;
    t += dt;
  }
}

// ---------------------------------------------------------------------------
// Layers 1/2 recurrence over one time-chunk; 1 xw float per lane per step,
// prefetched 3 deep; h/c carried across chunks.
// ---------------------------------------------------------------------------
template<typename ST>
__global__ __launch_bounds__(256, 1) void k_recur12(const float* __restrict__ xwF,
                                                    const float* __restrict__ xwB,
                                                    const float* __restrict__ whh,
                                                    ST* __restrict__ seq,
                                                    float* __restrict__ hst, float* __restrict__ cst,
                                                    int initFlag, int tF0, int tB0, int TC) {
  const int wg = blockIdx.x, dir = wg >> 6, b = wg & 63;
  const int w4 = threadIdx.x >> 6, l = threadIdx.x & 63;
  const int gi = l & 3, j = w4 * 16 + (l >> 2);
  const float* xw = dir ? xwB : xwF;

  float w[HID];
  {
    const float* W = whh + ((size_t)dir * G4 + gi * HID + j) * HID;
#pragma unroll
    for (int k = 0; k < HID; ++k) w[k] = W[k];
  }

  __shared__ __align__(16) float h_lds[2][HID];
  const int sidx = (dir * BATCH + b) * HID + j;
  float c = 0.f;
  if (threadIdx.x < HID) {
    h_lds[0][threadIdx.x] = initFlag ? 0.f
        : hst[(dir * BATCH + b) * HID + threadIdx.x];
  }
  if ((l & 3) == 0 && !initFlag) c = cst[sidx];

  // lane's xw element within a row: gi*64 + j
  const int goff = gi * HID + j;
  auto ltAt = [&](int i) { int ii = (i > TC - 1) ? (TC - 1) : i; return dir ? (TC - 1 - ii) : ii; };
  float xcur = xw[((size_t)ltAt(0) * BATCH + b) * G4 + goff];
  float xn1  = xw[((size_t)ltAt(1) * BATCH + b) * G4 + goff];
  float xn2  = xw[((size_t)ltAt(2) * BATCH + b) * G4 + goff];

  int t = dir ? tB0 : tF0;
  const int dt = dir ? -1 : 1;
  bar_lds();

  int par = 0;
#pragma unroll 2
  for (int it = 0; it < TC; ++it) {
    const float xn3 = xw[((size_t)ltAt(it + 3) * BATCH + b) * G4 + goff];

    const float pre = dot64(&h_lds[par][0], w, xcur);
    const float hv = cell_update(pre, gi, c);

    if ((l & 3) == 0) {
      h_lds[par ^ 1][j] = hv;
      stv(&seq[((size_t)t * BATCH + b) * D2 + dir * HID + j], hv);
    }
    bar_lds();
    par ^= 1;
    xcur = xn1; xn1 = xn2; xn2 = xn3;
    t += dt;
  }
  if ((l & 3) == 0) {
    hst[sidx] = h_lds[par][j];
    cst[sidx] = c;
  }
}

// ---------------------------------------------------------------------------
// Layers 1/2 input GEMM over a row range (unchanged).
// ---------------------------------------------------------------------------
template<typename ST>
__global__ __launch_bounds__(128) void k_gemm12(const ST* __restrict__ seq,
                                                const float* __restrict__ wih,
                                                const float* __restrict__ bih,
                                                const float* __restrict__ bhh,
                                                float* __restrict__ xw, int rowoff) {
  __shared__ float in_lds[64][64];
  __shared__ float w_lds[256][32];
  const int tid = threadIdx.x;
  const int cg = tid & 31;
  const int rg = tid >> 5;
  const size_t gr0 = (size_t)rowoff + (size_t)blockIdx.x * 64;
  const size_t lr0 = (size_t)blockIdx.x * 64;

  float acc[16][8];
#pragma unroll
  for (int rr = 0; rr < 16; ++rr)
#pragma unroll
    for (int j = 0; j < 8; ++j) acc[rr][j] = 0.f;

  for (int kh = 0; kh < 2; ++kh) {
    __syncthreads();
    if constexpr (__is_same(ST, float)) {
      float4* dst = reinterpret_cast<float4*>(&in_lds[0][0]);
      for (int e = tid; e < 64 * 16; e += 128) {
        int row = e >> 4, cf4 = e & 15;
        dst[e] = *reinterpret_cast<const float4*>(&seq[(gr0 + row) * D2 + kh * 64 + cf4 * 4]);
      }
    } else {
      float* dstf = &in_lds[0][0];
      const __half2* src = reinterpret_cast<const __half2*>(seq);
      for (int e = tid; e < 64 * 32; e += 128) {
        int row = e >> 5, ch2 = e & 31;
        float2 f = __half22float2(src[(gr0 + row) * (D2 / 2) + kh * 32 + ch2]);
        dstf[row * 64 + ch2 * 2]     = f.x;
        dstf[row * 64 + ch2 * 2 + 1] = f.y;
      }
    }
    for (int kc2 = 0; kc2 < 2; ++kc2) {
      __syncthreads();
      int k0 = kh * 64 + kc2 * 32;
      for (int e4 = tid * 4; e4 < 256 * 32; e4 += 128 * 4) {
        int cc = e4 >> 5, kk = e4 & 31;
        float4 v = *reinterpret_cast<const float4*>(&wih[(size_t)cc * D2 + k0 + kk]);
        *reinterpret_cast<float4*>(&w_lds[cc][kk ^ (((cc >> 3) & 7) << 2)]) = v;
      }
      __syncthreads();
#pragma unroll
      for (int k4 = 0; k4 < 8; ++k4) {
        float4 wv[8];
#pragma unroll
        for (int j = 0; j < 8; ++j)
          wv[j] = *reinterpret_cast<const float4*>(&w_lds[cg * 8 + j][(k4 * 4) ^ ((cg & 7) << 2)]);
#pragma unroll
        for (int rr = 0; rr < 16; ++rr) {
          float4 iv = *reinterpret_cast<const float4*>(&in_lds[rg * 16 + rr][kc2 * 32 + k4 * 4]);
#pragma unroll
          for (int j = 0; j < 8; ++j) {
            acc[rr][j] = fmaf(iv.x, wv[j].x, acc[rr][j]);
            acc[rr][j] = fmaf(iv.y, wv[j].y, acc[rr][j]);
            acc[rr][j] = fmaf(iv.z, wv[j].z, acc[rr][j]);
            acc[rr][j] = fmaf(iv.w, wv[j].w, acc[rr][j]);
          }
        }
      }
    }
  }
  float bb[8];
#pragma unroll
  for (int j = 0; j < 8; ++j) bb[j] = bih[cg * 8 + j] + bhh[cg * 8 + j];
#pragma unroll
  for (int rr = 0; rr < 16; ++rr) {
    float* orow = xw + (lr0 + rg * 16 + rr) * G4 + cg * 8;
    float4 o0 = { acc[rr][0] + bb[0], acc[rr][1] + bb[1], acc[rr][2] + bb[2], acc[rr][3] + bb[3] };
    float4 o1 = { acc[rr][4] + bb[4], acc[rr][5] + bb[5], acc[rr][6] + bb[6], acc[rr][7] + bb[7] };
    *reinterpret_cast<float4*>(orow) = o0;
    *reinterpret_cast<float4*>(orow + 4) = o1;
  }
}

// ---------------------------------------------------------------------------
// Head MLP.
// ---------------------------------------------------------------------------
template<typename ST>
__global__ __launch_bounds__(128) void k_head(const ST* __restrict__ seq,
                                              const float* __restrict__ Wc1, const float* __restrict__ bc1,
                                              const float* __restrict__ Wc2, const float* __restrict__ bc2,
                                              const float* __restrict__ Wc3, const float* __restrict__ bc3,
                                              float* __restrict__ out) {
  int b = blockIdx.x;
  int tid = threadIdx.x;
  __shared__ float fin[D2], z1[D2], z2[HID];
  if (tid < HID) fin[tid] = ldv(&seq[((size_t)(T_LEN - 1) * BATCH + b) * D2 + tid]);
  else           fin[tid] = ldv(&seq[(size_t)b * D2 + tid]);
  __syncthreads();
  float s = bc1[tid];
  for (int k = 0; k < D2; ++k) s = fmaf(fin[k], Wc1[(size_t)tid * D2 + k], s);
  z1[tid] = fmaxf(s, 0.f);
  __syncthreads();
  if (tid < HID) {
    float s2 = bc2[tid];
    for (int k = 0; k < D2; ++k) s2 = fmaf(z1[k], Wc2[(size_t)tid * D2 + k], s2);
    z2[tid] = fmaxf(s2, 0.f);
  }
  __syncthreads();
  if (tid < 20) {
    float s3 = bc3[tid];
    for (int k = 0; k < HID; ++k) s3 = fmaf(z2[k], Wc3[(size_t)tid * HID + k], s3);
    out[b * 20 + tid] = s3;
  }
}

// ---------------------------------------------------------------------------
template<typename ST>
static void run_all(const float* x, const float* Wp, const float* bp,
                    const float* w_ih0, const float* w_hh0, const float* b_ih0, const float* b_hh0,
                    const float* w_ih12, const float* w_hh12, const float* b_ih12, const float* b_hh12,
                    const float* Wc1, const float* bc1, const float* Wc2, const float* bc2,
                    const float* Wc3, const float* bc3,
                    float* out, char* ws, int TC, hipStream_t stream) {
  ST* seqA = (ST*)ws;
  ST* seqB = seqA + (size_t)NROW * D2;
  uintptr_t up = ((uintptr_t)(seqB + (size_t)NROW * D2) + 255) & ~(uintptr_t)255;
  float* xwF = (float*)up;
  float* xwB = xwF + (size_t)TC * BATCH * G4;
  float* hst = xwB + (size_t)TC * BATCH * G4;
  float* cst = hst + 2 * BATCH * HID;
  float* w0p = cst + 2 * BATCH * HID;
  float* b0p = w0p + 2 * G4 * CH;

  hipLaunchKernelGGL(k_prep0, dim3(2), dim3(256), 0, stream, Wp, bp, w_ih0, b_ih0, b_hh0, w0p, b0p);
  hipLaunchKernelGGL(k_recur0<ST>, dim3(128), dim3(256), 0, stream, x, w0p, b0p, w_hh0, seqA);

  int NC = T_LEN / TC;
  for (int l = 0; l < 2; ++l) {
    const float* wih0d = w_ih12 + (size_t)(l * 2) * G4 * D2;
    const float* wih1d = wih0d + (size_t)G4 * D2;
    const float* whh_l = w_hh12 + (size_t)(l * 2) * G4 * HID;
    const float* bi0 = b_ih12 + (size_t)(l * 2) * G4;
    const float* bh0 = b_hh12 + (size_t)(l * 2) * G4;
    ST* sin  = (l == 0) ? seqA : seqB;
    ST* sout = (l == 0) ? seqB : seqA;
    for (int c = 0; c < NC; ++c) {
      int cb = NC - 1 - c;
      hipLaunchKernelGGL(k_gemm12<ST>, dim3(TC), dim3(128), 0, stream,
                         sin, wih0d, bi0, bh0, xwF, c * TC * BATCH);
      hipLaunchKernelGGL(k_gemm12<ST>, dim3(TC), dim3(128), 0, stream,
                         sin, wih1d, bi0 + G4, bh0 + G4, xwB, cb * TC * BATCH);
      hipLaunchKernelGGL(k_recur12<ST>, dim3(128), dim3(256), 0, stream,
                         xwF, xwB, whh_l, sout, hst, cst, (c == 0) ? 1 : 0,
                         c * TC, cb * TC + TC - 1, TC);
    }
  }
  hipLaunchKernelGGL(k_head<ST>, dim3(BATCH), dim3(128), 0, stream,
                     seqA, Wc1, bc1, Wc2, bc2, Wc3, bc3, out);
}

extern "C" void kernel_launch(void* const* d_in, const int* in_sizes, int n_in,
                              void* d_out, int out_size, void* d_ws, size_t ws_size,
                              hipStream_t stream) {
  const float* x      = (const float*)d_in[0];
  const float* Wp     = (const float*)d_in[1];
  const float* bp     = (const float*)d_in[2];
  const float* w_ih0  = (const float*)d_in[3];
  const float* w_hh0  = (const float*)d_in[4];
  const float* b_ih0  = (const float*)d_in[5];
  const float* b_hh0  = (const float*)d_in[6];
  const float* w_ih12 = (const float*)d_in[7];
  const float* w_hh12 = (const float*)d_in[8];
  const float* b_ih12 = (const float*)d_in[9];
  const float* b_hh12 = (const float*)d_in[10];
  const float* Wc1    = (const float*)d_in[11];
  const float* bc1    = (const float*)d_in[12];
  const float* Wc2    = (const float*)d_in[13];
  const float* bc2    = (const float*)d_in[14];
  const float* Wc3    = (const float*)d_in[15];
  const float* bc3    = (const float*)d_in[16];
  float* out = (float*)d_out;
  char* ws = (char*)d_ws;

  auto need = [](bool half, int TC) -> size_t {
    size_t seqb  = (size_t)NROW * D2 * (half ? 2 : 4) * 2;
    size_t chunk = (size_t)2 * TC * BATCH * G4 * 4;
    size_t small = (size_t)(2 * 2 * BATCH * HID + 2 * G4 * CH + 2 * G4) * 4;
    return seqb + chunk + small + 1024;
  };

  struct Opt { bool h; int tc; };
  const Opt opts[] = { {false,625},{false,500},{false,250},{false,125},{false,100},
                       {true,625},{true,500},{true,250},{true,125},{true,100},{true,50},{true,25} };
  bool useHalf = true; int TC = 25;
  for (const Opt& o : opts) {
    if (need(o.h, o.tc) <= ws_size) { useHalf = o.h; TC = o.tc; break; }
  }

  if (!useHalf)
    run_all<float>(x, Wp, bp, w_ih0, w_hh0, b_ih0, b_hh0, w_ih12, w_hh12, b_ih12, b_hh12,
                   Wc1, bc1, Wc2, bc2, Wc3, bc3, out, ws, TC, stream);
  else
    run_all<__half>(x, Wp, bp, w_ih0, w_hh0, b_ih0, b_hh0, w_ih12, w_hh12, b_ih12, b_hh12,
                    Wc1, bc1, Wc2, bc2, Wc3, bc3, out, ws, TC, stream);
}

// Round 7
// 5941.208 us; speedup vs baseline: 1.0069x; 1.0069x over previous
//
#include <hip/hip_runtime.h>
#include <hip/hip_fp16.h>
#include <math.h>

#define T_LEN 2500
#define BATCH 64
#define CH    12
#define HID   64
#define G4    256   // 4*H
#define D2    128   // 2*H
#define NROW  (T_LEN*BATCH)

__device__ __forceinline__ float rcp_(float x){ return __builtin_amdgcn_rcpf(x); }
__device__ __forceinline__ float sig_(float x){ return rcp_(1.f + __expf(-x)); }

__device__ __forceinline__ float ldv(const float* p){ return *p; }
__device__ __forceinline__ float ldv(const __half* p){ return __half2float(*p); }
__device__ __forceinline__ void stv(float* p, float v){ *p = v; }
__device__ __forceinline__ void stv(__half* p, float v){ *p = __float2half(v); }

// Opaque pin: severs value provenance from memory so the compiler CANNOT
// rematerialize (re-load) it inside the loop; value must stay in a VGPR.
__device__ __forceinline__ void pinreg(float& v) { asm volatile("" : "+v"(v)); }

// quad_perm DPP move (full-rate VALU)
template<int CTRL>
__device__ __forceinline__ float qperm(float v) {
  return __int_as_float(__builtin_amdgcn_mov_dpp(__float_as_int(v), CTRL, 0xf, 0xf, true));
}

// Raw barrier: LDS-ordering only; does NOT drain vmcnt (global prefetch stays in flight).
__device__ __forceinline__ void bar_lds() {
  asm volatile("s_waitcnt lgkmcnt(0)" ::: "memory");
  __builtin_amdgcn_s_barrier();
  __builtin_amdgcn_sched_barrier(0);
}

// dot over K=64 from LDS-broadcast h, 4 independent chains.
__device__ __forceinline__ float dot64(const float* hr, const float* w, float seed) {
  float s0 = seed, s1 = 0.f, s2 = 0.f, s3 = 0.f;
#pragma unroll
  for (int k = 0; k < HID; k += 16) {
    const float4 a0 = *reinterpret_cast<const float4*>(&hr[k]);
    const float4 a1 = *reinterpret_cast<const float4*>(&hr[k + 4]);
    const float4 a2 = *reinterpret_cast<const float4*>(&hr[k + 8]);
    const float4 a3 = *reinterpret_cast<const float4*>(&hr[k + 12]);
    s0 = fmaf(a0.x, w[k], s0);      s0 = fmaf(a0.y, w[k + 1], s0);
    s0 = fmaf(a0.z, w[k + 2], s0);  s0 = fmaf(a0.w, w[k + 3], s0);
    s1 = fmaf(a1.x, w[k + 4], s1);  s1 = fmaf(a1.y, w[k + 5], s1);
    s1 = fmaf(a1.z, w[k + 6], s1);  s1 = fmaf(a1.w, w[k + 7], s1);
    s2 = fmaf(a2.x, w[k + 8], s2);  s2 = fmaf(a2.y, w[k + 9], s2);
    s2 = fmaf(a2.z, w[k + 10], s2); s2 = fmaf(a2.w, w[k + 11], s2);
    s3 = fmaf(a3.x, w[k + 12], s3); s3 = fmaf(a3.y, w[k + 13], s3);
    s3 = fmaf(a3.z, w[k + 14], s3); s3 = fmaf(a3.w, w[k + 15], s3);
  }
  return (s0 + s1) + (s2 + s3);
}

// Per-lane gate nonlinearity (gi==2 -> tanh, else sigmoid), then quad-gather
// into leader (gi==0) and cell update. All lanes compute; only leader's valid.
__device__ __forceinline__ float cell_update(float v, int gi, float& c) {
  const float z = (gi == 2) ? (v + v) : v;
  const float y = sig_(z);
  const float act = (gi == 2) ? fmaf(2.f, y, -1.f) : y;
  const float t1 = qperm<0xB1>(act);   // lane^1
  const float t2 = qperm<0x4E>(act);   // lane^2
  const float t3 = qperm<0x4E>(t1);    // lane^3
  // leader: act=i, t1=f, t2=g, t3=o
  c = fmaf(t1, c, act * t2);
  const float y2 = sig_(c + c);
  const float th = fmaf(2.f, y2, -1.f);   // tanh(c)
  return t3 * th;
}

// ---------------------------------------------------------------------------
// Fold input projection into layer-0 input weights.
// ---------------------------------------------------------------------------
__global__ void k_prep0(const float* __restrict__ Wp, const float* __restrict__ bp,
                        const float* __restrict__ w_ih0,
                        const float* __restrict__ b_ih0, const float* __restrict__ b_hh0,
                        float* __restrict__ w0p, float* __restrict__ b0p) {
  int tid = blockIdx.x * blockDim.x + threadIdx.x;
  if (tid >= 2 * G4) return;
  const float* wih = w_ih0 + (size_t)tid * HID;
  float bb = b_ih0[tid] + b_hh0[tid];
  for (int j = 0; j < HID; ++j) bb += wih[j] * bp[j];
  b0p[tid] = bb;
  for (int c = 0; c < CH; ++c) {
    float s = 0.f;
    for (int j = 0; j < HID; ++j) s += wih[j] * Wp[j * CH + c];
    w0p[(size_t)tid * CH + c] = s;
  }
}

// ---------------------------------------------------------------------------
// Layer-0 recurrence. WG per (dir,b), 256 thr = 4 waves.
// lane -> (unit j = w*16 + l/4, gate gi = l&3); 64 weight VGPRs per lane.
// amdgpu_waves_per_eu(1,1): target exactly 1 wave/EU so the allocator budget
// is 512 VGPRs (round-6: heuristic targeted 8 waves/EU -> 64 VGPRs -> weights
// re-loaded every step). pinreg() additionally forbids rematerialization.
// ---------------------------------------------------------------------------
template<typename ST>
__global__ __attribute__((amdgpu_waves_per_eu(1, 1)))
__launch_bounds__(256, 1) void k_recur0(const float* __restrict__ x,
                                        const float* __restrict__ w0p,
                                        const float* __restrict__ b0p,
                                        const float* __restrict__ whh,
                                        ST* __restrict__ seq) {
  const int wg = blockIdx.x, dir = wg >> 6, b = wg & 63;
  const int w4 = threadIdx.x >> 6, l = threadIdx.x & 63;
  const int gi = l & 3, j = w4 * 16 + (l >> 2);
  const int row = dir * G4 + gi * HID + j;

  float w[HID];
  {
    const float* W = whh + (size_t)row * HID;
#pragma unroll
    for (int k = 0; k < HID; ++k) w[k] = W[k];
  }
#pragma unroll
  for (int k = 0; k < HID; ++k) pinreg(w[k]);

  float w0[CH];
  {
    const float* P = w0p + (size_t)row * CH;
#pragma unroll
    for (int c = 0; c < CH; ++c) w0[c] = P[c];
  }
#pragma unroll
  for (int c = 0; c < CH; ++c) pinreg(w0[c]);

  float bb = b0p[row];
  pinreg(bb);

  __shared__ __align__(16) float h_lds[2][HID];
  if (threadIdx.x < HID) { h_lds[0][threadIdx.x] = 0.f; }
  float c = 0.f;

  int t = dir ? (T_LEN - 1) : 0;
  const int dt = dir ? -1 : 1;
  const float* xb = x + (size_t)b * CH * T_LEN;

  float xc[CH], xn[CH];
#pragma unroll
  for (int cc = 0; cc < CH; ++cc) xc[cc] = xb[(size_t)cc * T_LEN + t];
  {
    const int t1 = t + dt;
#pragma unroll
    for (int cc = 0; cc < CH; ++cc) xn[cc] = xb[(size_t)cc * T_LEN + t1];
  }
  bar_lds();

  int par = 0;
#pragma unroll 2
  for (int it = 0; it < T_LEN; ++it) {
    // seed = bias + input projection (uses xc = x[t])
    float p0 = bb, p1 = 0.f, p2 = 0.f;
#pragma unroll
    for (int cc = 0; cc < 4; ++cc)  p0 = fmaf(xc[cc], w0[cc], p0);
#pragma unroll
    for (int cc = 4; cc < 8; ++cc)  p1 = fmaf(xc[cc], w0[cc], p1);
#pragma unroll
    for (int cc = 8; cc < 12; ++cc) p2 = fmaf(xc[cc], w0[cc], p2);

    // shift prefetch and issue loads for t+2 (overlaps the dot below)
#pragma unroll
    for (int cc = 0; cc < CH; ++cc) xc[cc] = xn[cc];
    {
      int t2 = t + 2 * dt;
      t2 = (t2 < 0) ? 0 : ((t2 > T_LEN - 1) ? (T_LEN - 1) : t2);
#pragma unroll
      for (int cc = 0; cc < CH; ++cc) xn[cc] = xb[(size_t)cc * T_LEN + t2];
    }

    const float pre = dot64(&h_lds[par][0], w, (p0 + p1) + p2);
    const float hv = cell_update(pre, gi, c);

    if ((l & 3) == 0) {
      h_lds[par ^ 1][j] = hv;
      stv(&seq[((size_t)t * BATCH + b) * D2 + dir * HID + j], hv);
    }
    bar_lds();
    par ^= 1;
    t += dt;
  }
}

// ---------------------------------------------------------------------------
// Layers 1/2 recurrence over one time-chunk; 1 xw float per lane per step,
// prefetched 3 deep; h/c carried across chunks.
// ---------------------------------------------------------------------------
template<typename ST>
__global__ __attribute__((amdgpu_waves_per_eu(1, 1)))
__launch_bounds__(256, 1) void k_recur12(const float* __restrict__ xwF,
                                         const float* __restrict__ xwB,
                                         const float* __restrict__ whh,
                                         ST* __restrict__ seq,
                                         float* __restrict__ hst, float* __restrict__ cst,
                                         int initFlag, int tF0, int tB0, int TC) {
  const int wg = blockIdx.x, dir = wg >> 6, b = wg & 63;
  const int w4 = threadIdx.x >> 6, l = threadIdx.x & 63;
  const int gi = l & 3, j = w4 * 16 + (l >> 2);
  const float* xw = dir ? xwB : xwF;

  float w[HID];
  {
    const float* W = whh + ((size_t)dir * G4 + gi * HID + j) * HID;
#pragma unroll
    for (int k = 0; k < HID; ++k) w[k] = W[k];
  }
#pragma unroll
  for (int k = 0; k < HID; ++k) pinreg(w[k]);

  __shared__ __align__(16) float h_lds[2][HID];
  const int sidx = (dir * BATCH + b) * HID + j;
  float c = 0.f;
  if (threadIdx.x < HID) {
    h_lds[0][threadIdx.x] = initFlag ? 0.f
        : hst[(dir * BATCH + b) * HID + threadIdx.x];
  }
  if ((l & 3) == 0 && !initFlag) c = cst[sidx];

  // lane's xw element within a row: gi*64 + j
  const int goff = gi * HID + j;
  auto ltAt = [&](int i) { int ii = (i > TC - 1) ? (TC - 1) : i; return dir ? (TC - 1 - ii) : ii; };
  float xcur = xw[((size_t)ltAt(0) * BATCH + b) * G4 + goff];
  float xn1  = xw[((size_t)ltAt(1) * BATCH + b) * G4 + goff];
  float xn2  = xw[((size_t)ltAt(2) * BATCH + b) * G4 + goff];

  int t = dir ? tB0 : tF0;
  const int dt = dir ? -1 : 1;
  bar_lds();

  int par = 0;
#pragma unroll 2
  for (int it = 0; it < TC; ++it) {
    const float xn3 = xw[((size_t)ltAt(it + 3) * BATCH + b) * G4 + goff];

    const float pre = dot64(&h_lds[par][0], w, xcur);
    const float hv = cell_update(pre, gi, c);

    if ((l & 3) == 0) {
      h_lds[par ^ 1][j] = hv;
      stv(&seq[((size_t)t * BATCH + b) * D2 + dir * HID + j], hv);
    }
    bar_lds();
    par ^= 1;
    xcur = xn1; xn1 = xn2; xn2 = xn3;
    t += dt;
  }
  if ((l & 3) == 0) {
    hst[sidx] = h_lds[par][j];
    cst[sidx] = c;
  }
}

// ---------------------------------------------------------------------------
// Layers 1/2 input GEMM over a row range (unchanged).
// ---------------------------------------------------------------------------
template<typename ST>
__global__ __launch_bounds__(128) void k_gemm12(const ST* __restrict__ seq,
                                                const float* __restrict__ wih,
                                                const float* __restrict__ bih,
                                                const float* __restrict__ bhh,
                                                float* __restrict__ xw, int rowoff) {
  __shared__ float in_lds[64][64];
  __shared__ float w_lds[256][32];
  const int tid = threadIdx.x;
  const int cg = tid & 31;
  const int rg = tid >> 5;
  const size_t gr0 = (size_t)rowoff + (size_t)blockIdx.x * 64;
  const size_t lr0 = (size_t)blockIdx.x * 64;

  float acc[16][8];
#pragma unroll
  for (int rr = 0; rr < 16; ++rr)
#pragma unroll
    for (int j = 0; j < 8; ++j) acc[rr][j] = 0.f;

  for (int kh = 0; kh < 2; ++kh) {
    __syncthreads();
    if constexpr (__is_same(ST, float)) {
      float4* dst = reinterpret_cast<float4*>(&in_lds[0][0]);
      for (int e = tid; e < 64 * 16; e += 128) {
        int row = e >> 4, cf4 = e & 15;
        dst[e] = *reinterpret_cast<const float4*>(&seq[(gr0 + row) * D2 + kh * 64 + cf4 * 4]);
      }
    } else {
      float* dstf = &in_lds[0][0];
      const __half2* src = reinterpret_cast<const __half2*>(seq);
      for (int e = tid; e < 64 * 32; e += 128) {
        int row = e >> 5, ch2 = e & 31;
        float2 f = __half22float2(src[(gr0 + row) * (D2 / 2) + kh * 32 + ch2]);
        dstf[row * 64 + ch2 * 2]     = f.x;
        dstf[row * 64 + ch2 * 2 + 1] = f.y;
      }
    }
    for (int kc2 = 0; kc2 < 2; ++kc2) {
      __syncthreads();
      int k0 = kh * 64 + kc2 * 32;
      for (int e4 = tid * 4; e4 < 256 * 32; e4 += 128 * 4) {
        int cc = e4 >> 5, kk = e4 & 31;
        float4 v = *reinterpret_cast<const float4*>(&wih[(size_t)cc * D2 + k0 + kk]);
        *reinterpret_cast<float4*>(&w_lds[cc][kk ^ (((cc >> 3) & 7) << 2)]) = v;
      }
      __syncthreads();
#pragma unroll
      for (int k4 = 0; k4 < 8; ++k4) {
        float4 wv[8];
#pragma unroll
        for (int j = 0; j < 8; ++j)
          wv[j] = *reinterpret_cast<const float4*>(&w_lds[cg * 8 + j][(k4 * 4) ^ ((cg & 7) << 2)]);
#pragma unroll
        for (int rr = 0; rr < 16; ++rr) {
          float4 iv = *reinterpret_cast<const float4*>(&in_lds[rg * 16 + rr][kc2 * 32 + k4 * 4]);
#pragma unroll
          for (int j = 0; j < 8; ++j) {
            acc[rr][j] = fmaf(iv.x, wv[j].x, acc[rr][j]);
            acc[rr][j] = fmaf(iv.y, wv[j].y, acc[rr][j]);
            acc[rr][j] = fmaf(iv.z, wv[j].z, acc[rr][j]);
            acc[rr][j] = fmaf(iv.w, wv[j].w, acc[rr][j]);
          }
        }
      }
    }
  }
  float bb[8];
#pragma unroll
  for (int j = 0; j < 8; ++j) bb[j] = bih[cg * 8 + j] + bhh[cg * 8 + j];
#pragma unroll
  for (int rr = 0; rr < 16; ++rr) {
    float* orow = xw + (lr0 + rg * 16 + rr) * G4 + cg * 8;
    float4 o0 = { acc[rr][0] + bb[0], acc[rr][1] + bb[1], acc[rr][2] + bb[2], acc[rr][3] + bb[3] };
    float4 o1 = { acc[rr][4] + bb[4], acc[rr][5] + bb[5], acc[rr][6] + bb[6], acc[rr][7] + bb[7] };
    *reinterpret_cast<float4*>(orow) = o0;
    *reinterpret_cast<float4*>(orow + 4) = o1;
  }
}

// ---------------------------------------------------------------------------
// Head MLP.
// ---------------------------------------------------------------------------
template<typename ST>
__global__ __launch_bounds__(128) void k_head(const ST* __restrict__ seq,
                                              const float* __restrict__ Wc1, const float* __restrict__ bc1,
                                              const float* __restrict__ Wc2, const float* __restrict__ bc2,
                                              const float* __restrict__ Wc3, const float* __restrict__ bc3,
                                              float* __restrict__ out) {
  int b = blockIdx.x;
  int tid = threadIdx.x;
  __shared__ float fin[D2], z1[D2], z2[HID];
  if (tid < HID) fin[tid] = ldv(&seq[((size_t)(T_LEN - 1) * BATCH + b) * D2 + tid]);
  else           fin[tid] = ldv(&seq[(size_t)b * D2 + tid]);
  __syncthreads();
  float s = bc1[tid];
  for (int k = 0; k < D2; ++k) s = fmaf(fin[k], Wc1[(size_t)tid * D2 + k], s);
  z1[tid] = fmaxf(s, 0.f);
  __syncthreads();
  if (tid < HID) {
    float s2 = bc2[tid];
    for (int k = 0; k < D2; ++k) s2 = fmaf(z1[k], Wc2[(size_t)tid * D2 + k], s2);
    z2[tid] = fmaxf(s2, 0.f);
  }
  __syncthreads();
  if (tid < 20) {
    float s3 = bc3[tid];
    for (int k = 0; k < HID; ++k) s3 = fmaf(z2[k], Wc3[(size_t)tid * HID + k], s3);
    out[b * 20 + tid] = s3;
  }
}

// ---------------------------------------------------------------------------
template<typename ST>
static void run_all(const float* x, const float* Wp, const float* bp,
                    const float* w_ih0, const float* w_hh0, const float* b_ih0, const float* b_hh0,
                    const float* w_ih12, const float* w_hh12, const float* b_ih12, const float* b_hh12,
                    const float* Wc1, const float* bc1, const float* Wc2, const float* bc2,
                    const float* Wc3, const float* bc3,
                    float* out, char* ws, int TC, hipStream_t stream) {
  ST* seqA = (ST*)ws;
  ST* seqB = seqA + (size_t)NROW * D2;
  uintptr_t up = ((uintptr_t)(seqB + (size_t)NROW * D2) + 255) & ~(uintptr_t)255;
  float* xwF = (float*)up;
  float* xwB = xwF + (size_t)TC * BATCH * G4;
  float* hst = xwB + (size_t)TC * BATCH * G4;
  float* cst = hst + 2 * BATCH * HID;
  float* w0p = cst + 2 * BATCH * HID;
  float* b0p = w0p + 2 * G4 * CH;

  hipLaunchKernelGGL(k_prep0, dim3(2), dim3(256), 0, stream, Wp, bp, w_ih0, b_ih0, b_hh0, w0p, b0p);
  hipLaunchKernelGGL(k_recur0<ST>, dim3(128), dim3(256), 0, stream, x, w0p, b0p, w_hh0, seqA);

  int NC = T_LEN / TC;
  for (int l = 0; l < 2; ++l) {
    const float* wih0d = w_ih12 + (size_t)(l * 2) * G4 * D2;
    const float* wih1d = wih0d + (size_t)G4 * D2;
    const float* whh_l = w_hh12 + (size_t)(l * 2) * G4 * HID;
    const float* bi0 = b_ih12 + (size_t)(l * 2) * G4;
    const float* bh0 = b_hh12 + (size_t)(l * 2) * G4;
    ST* sin  = (l == 0) ? seqA : seqB;
    ST* sout = (l == 0) ? seqB : seqA;
    for (int c = 0; c < NC; ++c) {
      int cb = NC - 1 - c;
      hipLaunchKernelGGL(k_gemm12<ST>, dim3(TC), dim3(128), 0, stream,
                         sin, wih0d, bi0, bh0, xwF, c * TC * BATCH);
      hipLaunchKernelGGL(k_gemm12<ST>, dim3(TC), dim3(128), 0, stream,
                         sin, wih1d, bi0 + G4, bh0 + G4, xwB, cb * TC * BATCH);
      hipLaunchKernelGGL(k_recur12<ST>, dim3(128), dim3(256), 0, stream,
                         xwF, xwB, whh_l, sout, hst, cst, (c == 0) ? 1 : 0,
                         c * TC, cb * TC + TC - 1, TC);
    }
  }
  hipLaunchKernelGGL(k_head<ST>, dim3(BATCH), dim3(128), 0, stream,
                     seqA, Wc1, bc1, Wc2, bc2, Wc3, bc3, out);
}

extern "C" void kernel_launch(void* const* d_in, const int* in_sizes, int n_in,
                              void* d_out, int out_size, void* d_ws, size_t ws_size,
                              hipStream_t stream) {
  const float* x      = (const float*)d_in[0];
  const float* Wp     = (const float*)d_in[1];
  const float* bp     = (const float*)d_in[2];
  const float* w_ih0  = (const float*)d_in[3];
  const float* w_hh0  = (const float*)d_in[4];
  const float* b_ih0  = (const float*)d_in[5];
  const float* b_hh0  = (const float*)d_in[6];
  const float* w_ih12 = (const float*)d_in[7];
  const float* w_hh12 = (const float*)d_in[8];
  const float* b_ih12 = (const float*)d_in[9];
  const float* b_hh12 = (const float*)d_in[10];
  const float* Wc1    = (const float*)d_in[11];
  const float* bc1    = (const float*)d_in[12];
  const float* Wc2    = (const float*)d_in[13];
  const float* bc2    = (const float*)d_in[14];
  const float* Wc3    = (const float*)d_in[15];
  const float* bc3    = (const float*)d_in[16];
  float* out = (float*)d_out;
  char* ws = (char*)d_ws;

  auto need = [](bool half, int TC) -> size_t {
    size_t seqb  = (size_t)NROW * D2 * (half ? 2 : 4) * 2;
    size_t chunk = (size_t)2 * TC * BATCH * G4 * 4;
    size_t small = (size_t)(2 * 2 * BATCH * HID + 2 * G4 * CH + 2 * G4) * 4;
    return seqb + chunk + small + 1024;
  };

  struct Opt { bool h; int tc; };
  const Opt opts[] = { {false,625},{false,500},{false,250},{false,125},{false,100},
                       {true,625},{true,500},{true,250},{true,125},{true,100},{true,50},{true,25} };
  bool useHalf = true; int TC = 25;
  for (const Opt& o : opts) {
    if (need(o.h, o.tc) <= ws_size) { useHalf = o.h; TC = o.tc; break; }
  }

  if (!useHalf)
    run_all<float>(x, Wp, bp, w_ih0, w_hh0, b_ih0, b_hh0, w_ih12, w_hh12, b_ih12, b_hh12,
                   Wc1, bc1, Wc2, bc2, Wc3, bc3, out, ws, TC, stream);
  else
    run_all<__half>(x, Wp, bp, w_ih0, w_hh0, b_ih0, b_hh0, w_ih12, w_hh12, b_ih12, b_hh12,
                    Wc1, bc1, Wc2, bc2, Wc3, bc3, out, ws, TC, stream);
}

// Round 8
// 4301.644 us; speedup vs baseline: 1.3907x; 1.3811x over previous
//
#include <hip/hip_runtime.h>
#include <hip/hip_fp16.h>
#include <math.h>

#define T_LEN 2500
#define BATCH 64
#define CH    12
#define HID   64
#define G4    256   // 4*H
#define D2    128   // 2*H
#define NROW  (T_LEN*BATCH)

typedef __attribute__((ext_vector_type(2))) float f32x2;
typedef __attribute__((ext_vector_type(4))) float f32x4;

__device__ __forceinline__ float rcp_(float x){ return __builtin_amdgcn_rcpf(x); }
__device__ __forceinline__ float sig_(float x){ return rcp_(1.f + __expf(-x)); }

__device__ __forceinline__ float ldv(const float* p){ return *p; }
__device__ __forceinline__ float ldv(const __half* p){ return __half2float(*p); }
__device__ __forceinline__ void stv(float* p, float v){ *p = v; }
__device__ __forceinline__ void stv(__half* p, float v){ *p = __float2half(v); }

// Opaque pins: forbid rematerialization; value must stay in VGPRs.
__device__ __forceinline__ void pinreg(float& v) { asm volatile("" : "+v"(v)); }
__device__ __forceinline__ void pinreg2(f32x2& v) { asm volatile("" : "+v"(v)); }
__device__ __forceinline__ void pinreg4(f32x4& v) { asm volatile("" : "+v"(v)); }

// quad_perm DPP move (full-rate VALU)
template<int CTRL>
__device__ __forceinline__ float qperm(float v) {
  return __int_as_float(__builtin_amdgcn_mov_dpp(__float_as_int(v), CTRL, 0xf, 0xf, true));
}
// sum over the 4 lanes of a quad (butterfly)
__device__ __forceinline__ float quad_sum(float v) {
  v += qperm<0xB1>(v);   // + lane^1
  v += qperm<0x4E>(v);   // + lane^2
  return v;
}

// Raw barrier: LDS-ordering only; does NOT drain vmcnt.
__device__ __forceinline__ void bar_lds() {
  asm volatile("s_waitcnt lgkmcnt(0)" ::: "memory");
  __builtin_amdgcn_s_barrier();
  __builtin_amdgcn_sched_barrier(0);
}

// VOP3P packed fma, h broadcast from a half of the pair operand (r4-proven).
__device__ __forceinline__ void pkfma_lo(f32x2& d, f32x2 h, f32x2 w) {
  asm("v_pk_fma_f32 %0, %1, %2, %0 op_sel:[0,0,0] op_sel_hi:[0,1,1]"
      : "+v"(d) : "v"(h), "v"(w));
}
__device__ __forceinline__ void pkfma_hi(f32x2& d, f32x2 h, f32x2 w) {
  asm("v_pk_fma_f32 %0, %1, %2, %0 op_sel:[1,0,0] op_sel_hi:[1,1,1]"
      : "+v"(d) : "v"(h), "v"(w));
}

// Per-lane partial dot over this lane's 16 k's (h quarter at hbase).
__device__ __forceinline__ void dot16(const float* hbase,
                                      const f32x2* w_if, const f32x2* w_go,
                                      f32x2& aif, f32x2& ago, f32x2& aif1, f32x2& ago1) {
#pragma unroll
  for (int m = 0; m < 4; ++m) {
    const f32x4 hh = *reinterpret_cast<const f32x4*>(hbase + m * 4);
    const f32x2 ha = __builtin_shufflevector(hh, hh, 0, 1);
    const f32x2 hb = __builtin_shufflevector(hh, hh, 2, 3);
    pkfma_lo(aif,  ha, w_if[4 * m + 0]); pkfma_lo(ago,  ha, w_go[4 * m + 0]);
    pkfma_hi(aif1, ha, w_if[4 * m + 1]); pkfma_hi(ago1, ha, w_go[4 * m + 1]);
    pkfma_lo(aif,  hb, w_if[4 * m + 2]); pkfma_lo(ago,  hb, w_go[4 * m + 2]);
    pkfma_hi(aif1, hb, w_if[4 * m + 3]); pkfma_hi(ago1, hb, w_go[4 * m + 3]);
  }
}

// Gate-q nonlinearity + quad gather + cell update (leader q==0 valid).
__device__ __forceinline__ float cell_update(float v, int gi, float& c) {
  const float z = (gi == 2) ? (v + v) : v;
  const float y = sig_(z);
  const float act = (gi == 2) ? fmaf(2.f, y, -1.f) : y;
  const float t1 = qperm<0xB1>(act);
  const float t2 = qperm<0x4E>(act);
  const float t3 = qperm<0x4E>(t1);
  c = fmaf(t1, c, act * t2);
  const float y2 = sig_(c + c);
  const float th = fmaf(2.f, y2, -1.f);   // tanh(c)
  return t3 * th;
}

// ---------------------------------------------------------------------------
// Prep: permute all recurrent weights into per-lane packed form.
// Lane tid4 = w4*64 + u*4 + q owns unit j=w4*16+u, k-quarter q.
//   whpk*: [dir|L][kl 0..15][tid4][4] = {Wi,Wf,Wg,Wo}[j][k=q*16+kl]
//   w0pk : [dir][ci 0..2][tid4][4]    = folded (Wih0·Wp)[gate][j][c=q*3+ci]
//   b0pk : [dir][tid4][4]             = gate biases for q==0 lanes, else 0
// ---------------------------------------------------------------------------
__global__ void k_prep(const float* __restrict__ Wp, const float* __restrict__ bp,
                       const float* __restrict__ w_ih0, const float* __restrict__ w_hh0,
                       const float* __restrict__ b_ih0, const float* __restrict__ b_hh0,
                       const float* __restrict__ w_hh12,
                       float* __restrict__ whpk0, float* __restrict__ whpk12,
                       float* __restrict__ w0pk, float* __restrict__ b0pk) {
  const int tid = blockIdx.x * blockDim.x + threadIdx.x;
  if (tid >= 512) return;
  const int dir = tid >> 8, tid4 = tid & 255;
  const int w4 = tid4 >> 6, l = tid4 & 63, u = l >> 2, q = l & 3, j = w4 * 16 + u;
  const int r0 = dir * G4 + 0 * HID + j, r1 = dir * G4 + 1 * HID + j;
  const int r2 = dir * G4 + 2 * HID + j, r3 = dir * G4 + 3 * HID + j;

  for (int kl = 0; kl < 16; ++kl) {
    const int k = q * 16 + kl;
    f32x4 v = { w_hh0[(size_t)r0 * HID + k], w_hh0[(size_t)r1 * HID + k],
                w_hh0[(size_t)r2 * HID + k], w_hh0[(size_t)r3 * HID + k] };
    *reinterpret_cast<f32x4*>(&whpk0[(size_t)((dir * 16 + kl) * 256 + tid4) * 4]) = v;
    for (int L = 0; L < 2; ++L) {
      const float* W = w_hh12 + (size_t)(L * 2 + dir) * G4 * HID;
      f32x4 v2 = { W[(size_t)(0 * HID + j) * HID + k], W[(size_t)(1 * HID + j) * HID + k],
                   W[(size_t)(2 * HID + j) * HID + k], W[(size_t)(3 * HID + j) * HID + k] };
      *reinterpret_cast<f32x4*>(&whpk12[(size_t)(((L * 2 + dir) * 16 + kl) * 256 + tid4) * 4]) = v2;
    }
  }
  for (int ci = 0; ci < 3; ++ci) {
    const int c = q * 3 + ci;
    f32x4 v = {0.f, 0.f, 0.f, 0.f};
    const int rows[4] = {r0, r1, r2, r3};
    for (int g = 0; g < 4; ++g) {
      float s = 0.f;
      for (int m = 0; m < HID; ++m) s += w_ih0[(size_t)rows[g] * HID + m] * Wp[m * CH + c];
      v[g] = s;
    }
    *reinterpret_cast<f32x4*>(&w0pk[(size_t)((dir * 3 + ci) * 256 + tid4) * 4]) = v;
  }
  f32x4 bv = {0.f, 0.f, 0.f, 0.f};
  if (q == 0) {
    const int rows[4] = {r0, r1, r2, r3};
    for (int g = 0; g < 4; ++g) {
      float s = b_ih0[rows[g]] + b_hh0[rows[g]];
      for (int m = 0; m < HID; ++m) s += w_ih0[(size_t)rows[g] * HID + m] * bp[m];
      bv[g] = s;
    }
  }
  *reinterpret_cast<f32x4*>(&b0pk[(size_t)(dir * 256 + tid4) * 4]) = bv;
}

// ---------------------------------------------------------------------------
// Layer-0 recurrence. WG per (dir,b), 4 waves. Lane (u,q): unit j, k-quarter q.
// 4 ds_read_b128/lane/step (16/wave-group total, was 64) + pk-FMA dot +
// quad butterfly + DPP cell. One raw barrier per step; h double-buffered.
// ---------------------------------------------------------------------------
template<typename ST>
__global__ __attribute__((amdgpu_waves_per_eu(1, 1)))
__launch_bounds__(256, 1) void k_recur0(const float* __restrict__ x,
                                        const float* __restrict__ w0pk,
                                        const float* __restrict__ b0pk,
                                        const float* __restrict__ whpk,
                                        ST* __restrict__ seq) {
  const int wg = blockIdx.x, dir = wg >> 6, b = wg & 63;
  const int tid4 = threadIdx.x;
  const int w4 = tid4 >> 6, l = tid4 & 63, u = l >> 2, q = l & 3;
  const int j = w4 * 16 + u;

  f32x2 w_if[16], w_go[16];
#pragma unroll
  for (int kl = 0; kl < 16; ++kl) {
    const f32x4 v = *reinterpret_cast<const f32x4*>(&whpk[(size_t)((dir * 16 + kl) * 256 + tid4) * 4]);
    w_if[kl] = __builtin_shufflevector(v, v, 0, 1);
    w_go[kl] = __builtin_shufflevector(v, v, 2, 3);
  }
#pragma unroll
  for (int kl = 0; kl < 16; ++kl) { pinreg2(w_if[kl]); pinreg2(w_go[kl]); }

  f32x4 w0v[3];
#pragma unroll
  for (int ci = 0; ci < 3; ++ci)
    w0v[ci] = *reinterpret_cast<const f32x4*>(&w0pk[(size_t)((dir * 3 + ci) * 256 + tid4) * 4]);
#pragma unroll
  for (int ci = 0; ci < 3; ++ci) pinreg4(w0v[ci]);
  f32x4 bv = *reinterpret_cast<const f32x4*>(&b0pk[(size_t)(dir * 256 + tid4) * 4]);
  pinreg4(bv);

  __shared__ __align__(16) float h_lds[2][HID];
  if (tid4 < HID) h_lds[0][tid4] = 0.f;
  float c = 0.f;

  int t = dir ? (T_LEN - 1) : 0;
  const int dt = dir ? -1 : 1;
  const float* xb = x + (size_t)b * CH * T_LEN;
  const int c0 = q * 3;

  float xc[3], xn[3];
#pragma unroll
  for (int ci = 0; ci < 3; ++ci) xc[ci] = xb[(size_t)(c0 + ci) * T_LEN + t];
  {
    const int t1 = t + dt;
#pragma unroll
    for (int ci = 0; ci < 3; ++ci) xn[ci] = xb[(size_t)(c0 + ci) * T_LEN + t1];
  }
  bar_lds();

  int par = 0;
#pragma unroll 2
  for (int it = 0; it < T_LEN; ++it) {
    const float* hbase = &h_lds[par][q * 16];

    f32x2 aif = {bv.x, bv.y}, ago = {bv.z, bv.w};
    f32x2 aif1 = {0.f, 0.f}, ago1 = {0.f, 0.f};
    // input projection for this lane's 3 channels
#pragma unroll
    for (int ci = 0; ci < 3; ++ci) {
      aif.x = fmaf(xc[ci], w0v[ci].x, aif.x);
      aif.y = fmaf(xc[ci], w0v[ci].y, aif.y);
      ago.x = fmaf(xc[ci], w0v[ci].z, ago.x);
      ago.y = fmaf(xc[ci], w0v[ci].w, ago.y);
    }
    // shift prefetch; issue loads for t+2 (overlap with dot)
#pragma unroll
    for (int ci = 0; ci < 3; ++ci) xc[ci] = xn[ci];
    {
      int t2 = t + 2 * dt;
      t2 = (t2 < 0) ? 0 : ((t2 > T_LEN - 1) ? (T_LEN - 1) : t2);
#pragma unroll
      for (int ci = 0; ci < 3; ++ci) xn[ci] = xb[(size_t)(c0 + ci) * T_LEN + t2];
    }

    dot16(hbase, w_if, w_go, aif, ago, aif1, ago1);
    aif += aif1; ago += ago1;

    const float pi = quad_sum(aif.x), pf = quad_sum(aif.y);
    const float pg = quad_sum(ago.x), po = quad_sum(ago.y);
    const float v = (q == 0) ? pi : ((q == 1) ? pf : ((q == 2) ? pg : po));
    const float hv = cell_update(v, q, c);

    if (q == 0) {
      h_lds[par ^ 1][j] = hv;
      stv(&seq[((size_t)t * BATCH + b) * D2 + dir * HID + j], hv);
    }
    bar_lds();
    par ^= 1;
    t += dt;
  }
}

// ---------------------------------------------------------------------------
// Layers 1/2 recurrence over one time-chunk; lane loads gate-q's xw value and
// seeds it into its pk slot (summed once by the butterfly). h/c carried.
// ---------------------------------------------------------------------------
template<typename ST>
__global__ __attribute__((amdgpu_waves_per_eu(1, 1)))
__launch_bounds__(256, 1) void k_recur12(const float* __restrict__ xwF,
                                         const float* __restrict__ xwB,
                                         const float* __restrict__ whpk,
                                         ST* __restrict__ seq,
                                         float* __restrict__ hst, float* __restrict__ cst,
                                         int initFlag, int tF0, int tB0, int TC) {
  const int wg = blockIdx.x, dir = wg >> 6, b = wg & 63;
  const int tid4 = threadIdx.x;
  const int w4 = tid4 >> 6, l = tid4 & 63, u = l >> 2, q = l & 3;
  const int j = w4 * 16 + u;
  const float* xw = dir ? xwB : xwF;

  f32x2 w_if[16], w_go[16];
#pragma unroll
  for (int kl = 0; kl < 16; ++kl) {
    const f32x4 v = *reinterpret_cast<const f32x4*>(&whpk[(size_t)((dir * 16 + kl) * 256 + tid4) * 4]);
    w_if[kl] = __builtin_shufflevector(v, v, 0, 1);
    w_go[kl] = __builtin_shufflevector(v, v, 2, 3);
  }
#pragma unroll
  for (int kl = 0; kl < 16; ++kl) { pinreg2(w_if[kl]); pinreg2(w_go[kl]); }

  __shared__ __align__(16) float h_lds[2][HID];
  const int sidx = (dir * BATCH + b) * HID + j;
  float c = 0.f;
  if (tid4 < HID)
    h_lds[0][tid4] = initFlag ? 0.f : hst[(dir * BATCH + b) * HID + tid4];
  if (q == 0 && !initFlag) c = cst[sidx];

  const int goff = q * HID + j;   // gate-q element for unit j
  auto ltAt = [&](int i) { int ii = (i > TC - 1) ? (TC - 1) : i; return dir ? (TC - 1 - ii) : ii; };
  float xcur = xw[((size_t)ltAt(0) * BATCH + b) * G4 + goff];
  float xn1  = xw[((size_t)ltAt(1) * BATCH + b) * G4 + goff];
  float xn2  = xw[((size_t)ltAt(2) * BATCH + b) * G4 + goff];

  int t = dir ? tB0 : tF0;
  const int dt = dir ? -1 : 1;
  bar_lds();

  int par = 0;
#pragma unroll 2
  for (int it = 0; it < TC; ++it) {
    const float xn3 = xw[((size_t)ltAt(it + 3) * BATCH + b) * G4 + goff];
    const float* hbase = &h_lds[par][q * 16];

    f32x2 aif = { (q == 0) ? xcur : 0.f, (q == 1) ? xcur : 0.f };
    f32x2 ago = { (q == 2) ? xcur : 0.f, (q == 3) ? xcur : 0.f };
    f32x2 aif1 = {0.f, 0.f}, ago1 = {0.f, 0.f};
    dot16(hbase, w_if, w_go, aif, ago, aif1, ago1);
    aif += aif1; ago += ago1;

    const float pi = quad_sum(aif.x), pf = quad_sum(aif.y);
    const float pg = quad_sum(ago.x), po = quad_sum(ago.y);
    const float v = (q == 0) ? pi : ((q == 1) ? pf : ((q == 2) ? pg : po));
    const float hv = cell_update(v, q, c);

    if (q == 0) {
      h_lds[par ^ 1][j] = hv;
      stv(&seq[((size_t)t * BATCH + b) * D2 + dir * HID + j], hv);
    }
    bar_lds();
    par ^= 1;
    xcur = xn1; xn1 = xn2; xn2 = xn3;
    t += dt;
  }
  if (q == 0) {
    hst[sidx] = h_lds[par][j];
    cst[sidx] = c;
  }
}

// ---------------------------------------------------------------------------
// Layers 1/2 input GEMM over a row range (unchanged).
// ---------------------------------------------------------------------------
template<typename ST>
__global__ __launch_bounds__(128) void k_gemm12(const ST* __restrict__ seq,
                                                const float* __restrict__ wih,
                                                const float* __restrict__ bih,
                                                const float* __restrict__ bhh,
                                                float* __restrict__ xw, int rowoff) {
  __shared__ float in_lds[64][64];
  __shared__ float w_lds[256][32];
  const int tid = threadIdx.x;
  const int cg = tid & 31;
  const int rg = tid >> 5;
  const size_t gr0 = (size_t)rowoff + (size_t)blockIdx.x * 64;
  const size_t lr0 = (size_t)blockIdx.x * 64;

  float acc[16][8];
#pragma unroll
  for (int rr = 0; rr < 16; ++rr)
#pragma unroll
    for (int j = 0; j < 8; ++j) acc[rr][j] = 0.f;

  for (int kh = 0; kh < 2; ++kh) {
    __syncthreads();
    if constexpr (__is_same(ST, float)) {
      float4* dst = reinterpret_cast<float4*>(&in_lds[0][0]);
      for (int e = tid; e < 64 * 16; e += 128) {
        int row = e >> 4, cf4 = e & 15;
        dst[e] = *reinterpret_cast<const float4*>(&seq[(gr0 + row) * D2 + kh * 64 + cf4 * 4]);
      }
    } else {
      float* dstf = &in_lds[0][0];
      const __half2* src = reinterpret_cast<const __half2*>(seq);
      for (int e = tid; e < 64 * 32; e += 128) {
        int row = e >> 5, ch2 = e & 31;
        float2 f = __half22float2(src[(gr0 + row) * (D2 / 2) + kh * 32 + ch2]);
        dstf[row * 64 + ch2 * 2]     = f.x;
        dstf[row * 64 + ch2 * 2 + 1] = f.y;
      }
    }
    for (int kc2 = 0; kc2 < 2; ++kc2) {
      __syncthreads();
      int k0 = kh * 64 + kc2 * 32;
      for (int e4 = tid * 4; e4 < 256 * 32; e4 += 128 * 4) {
        int cc = e4 >> 5, kk = e4 & 31;
        float4 v = *reinterpret_cast<const float4*>(&wih[(size_t)cc * D2 + k0 + kk]);
        *reinterpret_cast<float4*>(&w_lds[cc][kk ^ (((cc >> 3) & 7) << 2)]) = v;
      }
      __syncthreads();
#pragma unroll
      for (int k4 = 0; k4 < 8; ++k4) {
        float4 wv[8];
#pragma unroll
        for (int j = 0; j < 8; ++j)
          wv[j] = *reinterpret_cast<const float4*>(&w_lds[cg * 8 + j][(k4 * 4) ^ ((cg & 7) << 2)]);
#pragma unroll
        for (int rr = 0; rr < 16; ++rr) {
          float4 iv = *reinterpret_cast<const float4*>(&in_lds[rg * 16 + rr][kc2 * 32 + k4 * 4]);
#pragma unroll
          for (int j = 0; j < 8; ++j) {
            acc[rr][j] = fmaf(iv.x, wv[j].x, acc[rr][j]);
            acc[rr][j] = fmaf(iv.y, wv[j].y, acc[rr][j]);
            acc[rr][j] = fmaf(iv.z, wv[j].z, acc[rr][j]);
            acc[rr][j] = fmaf(iv.w, wv[j].w, acc[rr][j]);
          }
        }
      }
    }
  }
  float bb[8];
#pragma unroll
  for (int j = 0; j < 8; ++j) bb[j] = bih[cg * 8 + j] + bhh[cg * 8 + j];
#pragma unroll
  for (int rr = 0; rr < 16; ++rr) {
    float* orow = xw + (lr0 + rg * 16 + rr) * G4 + cg * 8;
    float4 o0 = { acc[rr][0] + bb[0], acc[rr][1] + bb[1], acc[rr][2] + bb[2], acc[rr][3] + bb[3] };
    float4 o1 = { acc[rr][4] + bb[4], acc[rr][5] + bb[5], acc[rr][6] + bb[6], acc[rr][7] + bb[7] };
    *reinterpret_cast<float4*>(orow) = o0;
    *reinterpret_cast<float4*>(orow + 4) = o1;
  }
}

// ---------------------------------------------------------------------------
// Head MLP (unchanged).
// ---------------------------------------------------------------------------
template<typename ST>
__global__ __launch_bounds__(128) void k_head(const ST* __restrict__ seq,
                                              const float* __restrict__ Wc1, const float* __restrict__ bc1,
                                              const float* __restrict__ Wc2, const float* __restrict__ bc2,
                                              const float* __restrict__ Wc3, const float* __restrict__ bc3,
                                              float* __restrict__ out) {
  int b = blockIdx.x;
  int tid = threadIdx.x;
  __shared__ float fin[D2], z1[D2], z2[HID];
  if (tid < HID) fin[tid] = ldv(&seq[((size_t)(T_LEN - 1) * BATCH + b) * D2 + tid]);
  else           fin[tid] = ldv(&seq[(size_t)b * D2 + tid]);
  __syncthreads();
  float s = bc1[tid];
  for (int k = 0; k < D2; ++k) s = fmaf(fin[k], Wc1[(size_t)tid * D2 + k], s);
  z1[tid] = fmaxf(s, 0.f);
  __syncthreads();
  if (tid < HID) {
    float s2 = bc2[tid];
    for (int k = 0; k < D2; ++k) s2 = fmaf(z1[k], Wc2[(size_t)tid * D2 + k], s2);
    z2[tid] = fmaxf(s2, 0.f);
  }
  __syncthreads();
  if (tid < 20) {
    float s3 = bc3[tid];
    for (int k = 0; k < HID; ++k) s3 = fmaf(z2[k], Wc3[(size_t)tid * HID + k], s3);
    out[b * 20 + tid] = s3;
  }
}

// ---------------------------------------------------------------------------
#define WHPK0_F  (2*16*256*4)
#define WHPK12_F (4*16*256*4)
#define W0PK_F   (2*3*256*4)
#define B0PK_F   (2*256*4)

template<typename ST>
static void run_all(const float* x, const float* Wp, const float* bp,
                    const float* w_ih0, const float* w_hh0, const float* b_ih0, const float* b_hh0,
                    const float* w_ih12, const float* w_hh12, const float* b_ih12, const float* b_hh12,
                    const float* Wc1, const float* bc1, const float* Wc2, const float* bc2,
                    const float* Wc3, const float* bc3,
                    float* out, char* ws, int TC, hipStream_t stream) {
  ST* seqA = (ST*)ws;
  ST* seqB = seqA + (size_t)NROW * D2;
  uintptr_t up = ((uintptr_t)(seqB + (size_t)NROW * D2) + 255) & ~(uintptr_t)255;
  float* xwF = (float*)up;
  float* xwB = xwF + (size_t)TC * BATCH * G4;
  float* hst = xwB + (size_t)TC * BATCH * G4;
  float* cst = hst + 2 * BATCH * HID;
  float* whpk0  = cst + 2 * BATCH * HID;
  float* whpk12 = whpk0 + WHPK0_F;
  float* w0pk   = whpk12 + WHPK12_F;
  float* b0pk   = w0pk + W0PK_F;

  hipLaunchKernelGGL(k_prep, dim3(2), dim3(256), 0, stream,
                     Wp, bp, w_ih0, w_hh0, b_ih0, b_hh0, w_hh12,
                     whpk0, whpk12, w0pk, b0pk);
  hipLaunchKernelGGL(k_recur0<ST>, dim3(128), dim3(256), 0, stream, x, w0pk, b0pk, whpk0, seqA);

  int NC = T_LEN / TC;
  for (int l = 0; l < 2; ++l) {
    const float* wih0d = w_ih12 + (size_t)(l * 2) * G4 * D2;
    const float* wih1d = wih0d + (size_t)G4 * D2;
    const float* bi0 = b_ih12 + (size_t)(l * 2) * G4;
    const float* bh0 = b_hh12 + (size_t)(l * 2) * G4;
    const float* whpk_l = whpk12 + (size_t)l * 2 * 16 * 256 * 4;
    ST* sin  = (l == 0) ? seqA : seqB;
    ST* sout = (l == 0) ? seqB : seqA;
    for (int c = 0; c < NC; ++c) {
      int cb = NC - 1 - c;
      hipLaunchKernelGGL(k_gemm12<ST>, dim3(TC), dim3(128), 0, stream,
                         sin, wih0d, bi0, bh0, xwF, c * TC * BATCH);
      hipLaunchKernelGGL(k_gemm12<ST>, dim3(TC), dim3(128), 0, stream,
                         sin, wih1d, bi0 + G4, bh0 + G4, xwB, cb * TC * BATCH);
      hipLaunchKernelGGL(k_recur12<ST>, dim3(128), dim3(256), 0, stream,
                         xwF, xwB, whpk_l, sout, hst, cst, (c == 0) ? 1 : 0,
                         c * TC, cb * TC + TC - 1, TC);
    }
  }
  hipLaunchKernelGGL(k_head<ST>, dim3(BATCH), dim3(128), 0, stream,
                     seqA, Wc1, bc1, Wc2, bc2, Wc3, bc3, out);
}

extern "C" void kernel_launch(void* const* d_in, const int* in_sizes, int n_in,
                              void* d_out, int out_size, void* d_ws, size_t ws_size,
                              hipStream_t stream) {
  const float* x      = (const float*)d_in[0];
  const float* Wp     = (const float*)d_in[1];
  const float* bp     = (const float*)d_in[2];
  const float* w_ih0  = (const float*)d_in[3];
  const float* w_hh0  = (const float*)d_in[4];
  const float* b_ih0  = (const float*)d_in[5];
  const float* b_hh0  = (const float*)d_in[6];
  const float* w_ih12 = (const float*)d_in[7];
  const float* w_hh12 = (const float*)d_in[8];
  const float* b_ih12 = (const float*)d_in[9];
  const float* b_hh12 = (const float*)d_in[10];
  const float* Wc1    = (const float*)d_in[11];
  const float* bc1    = (const float*)d_in[12];
  const float* Wc2    = (const float*)d_in[13];
  const float* bc2    = (const float*)d_in[14];
  const float* Wc3    = (const float*)d_in[15];
  const float* bc3    = (const float*)d_in[16];
  float* out = (float*)d_out;
  char* ws = (char*)d_ws;

  auto need = [](bool half, int TC) -> size_t {
    size_t seqb  = (size_t)NROW * D2 * (half ? 2 : 4) * 2;
    size_t chunk = (size_t)2 * TC * BATCH * G4 * 4;
    size_t small = (size_t)(2 * 2 * BATCH * HID + WHPK0_F + WHPK12_F + W0PK_F + B0PK_F) * 4;
    return seqb + chunk + small + 1024;
  };

  struct Opt { bool h; int tc; };
  const Opt opts[] = { {false,625},{false,500},{false,250},{false,125},{false,100},
                       {true,625},{true,500},{true,250},{true,125},{true,100},{true,50},{true,25} };
  bool useHalf = true; int TC = 25;
  for (const Opt& o : opts) {
    if (need(o.h, o.tc) <= ws_size) { useHalf = o.h; TC = o.tc; break; }
  }

  if (!useHalf)
    run_all<float>(x, Wp, bp, w_ih0, w_hh0, b_ih0, b_hh0, w_ih12, w_hh12, b_ih12, b_hh12,
                   Wc1, bc1, Wc2, bc2, Wc3, bc3, out, ws, TC, stream);
  else
    run_all<__half>(x, Wp, bp, w_ih0, w_hh0, b_ih0, b_hh0, w_ih12, w_hh12, b_ih12, b_hh12,
                    Wc1, bc1, Wc2, bc2, Wc3, bc3, out, ws, TC, stream);
}

// Round 9
// 3491.436 us; speedup vs baseline: 1.7134x; 1.2321x over previous
//
#include <hip/hip_runtime.h>
#include <math.h>

#define T_LEN 2500
#define BATCH 64
#define CH    12
#define HID   64
#define G4    256   // 4*H
#define D2    128   // 2*H
#define NROW  (T_LEN*BATCH)

typedef __attribute__((ext_vector_type(2))) float f32x2;
typedef __attribute__((ext_vector_type(4))) float f32x4;

__device__ __forceinline__ float rcp_(float x){ return __builtin_amdgcn_rcpf(x); }
__device__ __forceinline__ float sig_(float x){ return rcp_(1.f + __expf(-x)); }

// Opaque pins: forbid rematerialization; value must stay in VGPRs.
__device__ __forceinline__ void pinreg2(f32x2& v) { asm volatile("" : "+v"(v)); }
__device__ __forceinline__ void pinreg4(f32x4& v) { asm volatile("" : "+v"(v)); }

// quad_perm DPP move (full-rate VALU)
template<int CTRL>
__device__ __forceinline__ float qperm(float v) {
  return __int_as_float(__builtin_amdgcn_mov_dpp(__float_as_int(v), CTRL, 0xf, 0xf, true));
}
__device__ __forceinline__ float quad_sum(float v) {
  v += qperm<0xB1>(v);
  v += qperm<0x4E>(v);
  return v;
}

// Raw barrier: LDS-ordering only; does NOT drain vmcnt (prefetch stays in flight).
__device__ __forceinline__ void bar_lds() {
  asm volatile("s_waitcnt lgkmcnt(0)" ::: "memory");
  __builtin_amdgcn_s_barrier();
  __builtin_amdgcn_sched_barrier(0);
}

// VOP3P packed fma, h broadcast from a half of the pair operand (r8-proven).
__device__ __forceinline__ void pkfma_lo(f32x2& d, f32x2 h, f32x2 w) {
  asm("v_pk_fma_f32 %0, %1, %2, %0 op_sel:[0,0,0] op_sel_hi:[0,1,1]"
      : "+v"(d) : "v"(h), "v"(w));
}
__device__ __forceinline__ void pkfma_hi(f32x2& d, f32x2 h, f32x2 w) {
  asm("v_pk_fma_f32 %0, %1, %2, %0 op_sel:[1,0,0] op_sel_hi:[1,1,1]"
      : "+v"(d) : "v"(h), "v"(w));
}

// hh partial dot over this lane's 16 k's (h quarter at hbase).
__device__ __forceinline__ void dot16(const float* hbase,
                                      const f32x2* w_if, const f32x2* w_go,
                                      f32x2& aif, f32x2& ago, f32x2& aif1, f32x2& ago1) {
#pragma unroll
  for (int m = 0; m < 4; ++m) {
    const f32x4 hh = *reinterpret_cast<const f32x4*>(hbase + m * 4);
    const f32x2 ha = __builtin_shufflevector(hh, hh, 0, 1);
    const f32x2 hb = __builtin_shufflevector(hh, hh, 2, 3);
    pkfma_lo(aif,  ha, w_if[4 * m + 0]); pkfma_lo(ago,  ha, w_go[4 * m + 0]);
    pkfma_hi(aif1, ha, w_if[4 * m + 1]); pkfma_hi(ago1, ha, w_go[4 * m + 1]);
    pkfma_lo(aif,  hb, w_if[4 * m + 2]); pkfma_lo(ago,  hb, w_go[4 * m + 2]);
    pkfma_hi(aif1, hb, w_if[4 * m + 3]); pkfma_hi(ago1, hb, w_go[4 * m + 3]);
  }
}

// Gate-q nonlinearity + quad gather + cell update (leader q==0 valid).
__device__ __forceinline__ float cell_update(float v, int gi, float& c) {
  const float z = (gi == 2) ? (v + v) : v;
  const float y = sig_(z);
  const float act = (gi == 2) ? fmaf(2.f, y, -1.f) : y;
  const float t1 = qperm<0xB1>(act);
  const float t2 = qperm<0x4E>(act);
  const float t3 = qperm<0x4E>(t1);
  c = fmaf(t1, c, act * t2);
  const float y2 = sig_(c + c);
  const float th = fmaf(2.f, y2, -1.f);   // tanh(c)
  return t3 * th;
}

// ---------------------------------------------------------------------------
// Prep: permute all weights into per-lane packed form.
// Lane tid4 = w4*64 + u*4 + q owns unit j=w4*16+u.
//   hh (K=64, quarter q):    kl in [0,16), k = q*16+kl
//   ih L1/2 (K=128):         kl = m*4+e,   k = m*16 + q*4 + e  (bank-disjoint)
//   b*pk: biases on q==0 lanes only (counted once per quad).
// ---------------------------------------------------------------------------
__global__ void k_prep(const float* __restrict__ Wp, const float* __restrict__ bp,
                       const float* __restrict__ w_ih0, const float* __restrict__ w_hh0,
                       const float* __restrict__ b_ih0, const float* __restrict__ b_hh0,
                       const float* __restrict__ w_ih12, const float* __restrict__ w_hh12,
                       const float* __restrict__ b_ih12, const float* __restrict__ b_hh12,
                       float* __restrict__ whpk0, float* __restrict__ whpk12,
                       float* __restrict__ wihpk12, float* __restrict__ b12pk,
                       float* __restrict__ w0pk, float* __restrict__ b0pk) {
  const int tid = blockIdx.x * blockDim.x + threadIdx.x;
  if (tid >= 512) return;
  const int dir = tid >> 8, tid4 = tid & 255;
  const int w4 = tid4 >> 6, l = tid4 & 63, u = l >> 2, q = l & 3, j = w4 * 16 + u;
  const int r0 = dir * G4 + 0 * HID + j, r1 = dir * G4 + 1 * HID + j;
  const int r2 = dir * G4 + 2 * HID + j, r3 = dir * G4 + 3 * HID + j;

  // hh packs (layer 0 and layers 1/2)
  for (int kl = 0; kl < 16; ++kl) {
    const int k = q * 16 + kl;
    f32x4 v = { w_hh0[(size_t)r0 * HID + k], w_hh0[(size_t)r1 * HID + k],
                w_hh0[(size_t)r2 * HID + k], w_hh0[(size_t)r3 * HID + k] };
    *reinterpret_cast<f32x4*>(&whpk0[(size_t)((dir * 16 + kl) * 256 + tid4) * 4]) = v;
    for (int L = 0; L < 2; ++L) {
      const float* W = w_hh12 + (size_t)(L * 2 + dir) * G4 * HID;
      f32x4 v2 = { W[(size_t)(0 * HID + j) * HID + k], W[(size_t)(1 * HID + j) * HID + k],
                   W[(size_t)(2 * HID + j) * HID + k], W[(size_t)(3 * HID + j) * HID + k] };
      *reinterpret_cast<f32x4*>(&whpk12[(size_t)(((L * 2 + dir) * 16 + kl) * 256 + tid4) * 4]) = v2;
    }
  }
  // ih packs for layers 1/2
  for (int kl = 0; kl < 32; ++kl) {
    const int m = kl >> 2, e = kl & 3;
    const int k = m * 16 + q * 4 + e;
    for (int L = 0; L < 2; ++L) {
      const float* W = w_ih12 + (size_t)(L * 2 + dir) * G4 * D2;
      f32x4 v2 = { W[(size_t)(0 * HID + j) * D2 + k], W[(size_t)(1 * HID + j) * D2 + k],
                   W[(size_t)(2 * HID + j) * D2 + k], W[(size_t)(3 * HID + j) * D2 + k] };
      *reinterpret_cast<f32x4*>(&wihpk12[(size_t)(((L * 2 + dir) * 32 + kl) * 256 + tid4) * 4]) = v2;
    }
  }
  // layer-1/2 biases
  for (int L = 0; L < 2; ++L) {
    f32x4 bv = {0.f, 0.f, 0.f, 0.f};
    if (q == 0) {
      const int base = (L * 2 + dir) * G4;
      bv.x = b_ih12[base + 0 * HID + j] + b_hh12[base + 0 * HID + j];
      bv.y = b_ih12[base + 1 * HID + j] + b_hh12[base + 1 * HID + j];
      bv.z = b_ih12[base + 2 * HID + j] + b_hh12[base + 2 * HID + j];
      bv.w = b_ih12[base + 3 * HID + j] + b_hh12[base + 3 * HID + j];
    }
    *reinterpret_cast<f32x4*>(&b12pk[(size_t)((L * 2 + dir) * 256 + tid4) * 4]) = bv;
  }
  // layer-0 folded input projection (3 channels per lane: c = q*3+ci)
  for (int ci = 0; ci < 3; ++ci) {
    const int c = q * 3 + ci;
    f32x4 v = {0.f, 0.f, 0.f, 0.f};
    const int rows[4] = {r0, r1, r2, r3};
#pragma unroll
    for (int g = 0; g < 4; ++g) {
      float s = 0.f;
      for (int m = 0; m < HID; ++m) s += w_ih0[(size_t)rows[g] * HID + m] * Wp[m * CH + c];
      v[g] = s;
    }
    *reinterpret_cast<f32x4*>(&w0pk[(size_t)((dir * 3 + ci) * 256 + tid4) * 4]) = v;
  }
  f32x4 bv = {0.f, 0.f, 0.f, 0.f};
  if (q == 0) {
    const int rows[4] = {r0, r1, r2, r3};
#pragma unroll
    for (int g = 0; g < 4; ++g) {
      float s = b_ih0[rows[g]] + b_hh0[rows[g]];
      for (int m = 0; m < HID; ++m) s += w_ih0[(size_t)rows[g] * HID + m] * bp[m];
      bv[g] = s;
    }
  }
  *reinterpret_cast<f32x4*>(&b0pk[(size_t)(dir * 256 + tid4) * 4]) = bv;
}

// ---------------------------------------------------------------------------
// Layer-0 recurrence (r8-proven, 845 us). WG per (dir,b), 4 waves.
// ---------------------------------------------------------------------------
__global__ __attribute__((amdgpu_waves_per_eu(1, 1)))
__launch_bounds__(256, 1) void k_recur0(const float* __restrict__ x,
                                        const float* __restrict__ w0pk,
                                        const float* __restrict__ b0pk,
                                        const float* __restrict__ whpk,
                                        float* __restrict__ seq) {
  const int wg = blockIdx.x, dir = wg >> 6, b = wg & 63;
  const int tid4 = threadIdx.x;
  const int w4 = tid4 >> 6, l = tid4 & 63, u = l >> 2, q = l & 3;
  const int j = w4 * 16 + u;

  f32x2 w_if[16], w_go[16];
#pragma unroll
  for (int kl = 0; kl < 16; ++kl) {
    const f32x4 v = *reinterpret_cast<const f32x4*>(&whpk[(size_t)((dir * 16 + kl) * 256 + tid4) * 4]);
    w_if[kl] = __builtin_shufflevector(v, v, 0, 1);
    w_go[kl] = __builtin_shufflevector(v, v, 2, 3);
  }
#pragma unroll
  for (int kl = 0; kl < 16; ++kl) { pinreg2(w_if[kl]); pinreg2(w_go[kl]); }

  f32x4 w0v[3];
#pragma unroll
  for (int ci = 0; ci < 3; ++ci)
    w0v[ci] = *reinterpret_cast<const f32x4*>(&w0pk[(size_t)((dir * 3 + ci) * 256 + tid4) * 4]);
#pragma unroll
  for (int ci = 0; ci < 3; ++ci) pinreg4(w0v[ci]);
  f32x4 bv = *reinterpret_cast<const f32x4*>(&b0pk[(size_t)(dir * 256 + tid4) * 4]);
  pinreg4(bv);

  __shared__ __align__(16) float h_lds[2][HID];
  if (tid4 < HID) h_lds[0][tid4] = 0.f;
  float c = 0.f;

  int t = dir ? (T_LEN - 1) : 0;
  const int dt = dir ? -1 : 1;
  const float* xb = x + (size_t)b * CH * T_LEN;
  const int c0 = q * 3;

  float xc[3], xn[3];
#pragma unroll
  for (int ci = 0; ci < 3; ++ci) xc[ci] = xb[(size_t)(c0 + ci) * T_LEN + t];
  {
    const int t1 = t + dt;
#pragma unroll
    for (int ci = 0; ci < 3; ++ci) xn[ci] = xb[(size_t)(c0 + ci) * T_LEN + t1];
  }
  bar_lds();

  int par = 0;
#pragma unroll 2
  for (int it = 0; it < T_LEN; ++it) {
    const float* hbase = &h_lds[par][q * 16];

    f32x2 aif = {bv.x, bv.y}, ago = {bv.z, bv.w};
    f32x2 aif1 = {0.f, 0.f}, ago1 = {0.f, 0.f};
#pragma unroll
    for (int ci = 0; ci < 3; ++ci) {
      aif.x = fmaf(xc[ci], w0v[ci].x, aif.x);
      aif.y = fmaf(xc[ci], w0v[ci].y, aif.y);
      ago.x = fmaf(xc[ci], w0v[ci].z, ago.x);
      ago.y = fmaf(xc[ci], w0v[ci].w, ago.y);
    }
#pragma unroll
    for (int ci = 0; ci < 3; ++ci) xc[ci] = xn[ci];
    {
      int t2 = t + 2 * dt;
      t2 = (t2 < 0) ? 0 : ((t2 > T_LEN - 1) ? (T_LEN - 1) : t2);
#pragma unroll
      for (int ci = 0; ci < 3; ++ci) xn[ci] = xb[(size_t)(c0 + ci) * T_LEN + t2];
    }

    dot16(hbase, w_if, w_go, aif, ago, aif1, ago1);
    aif += aif1; ago += ago1;

    const float pi = quad_sum(aif.x), pf = quad_sum(aif.y);
    const float pg = quad_sum(ago.x), po = quad_sum(ago.y);
    const float v = (q == 0) ? pi : ((q == 1) ? pf : ((q == 2) ? pg : po));
    const float hv = cell_update(v, q, c);

    if (q == 0) {
      h_lds[par ^ 1][j] = hv;
      seq[((size_t)t * BATCH + b) * D2 + dir * HID + j] = hv;
    }
    bar_lds();
    par ^= 1;
    t += dt;
  }
}

// ---------------------------------------------------------------------------
// Layers 1/2 FUSED recurrence: input GEMM folded into the chain's latency
// stalls. Per step each lane adds its 32-k ih partial (8 ds_read_b128 +
// 64 pk-FMA) into the same accumulators as the hh dot. seq rows staged by
// wave-0 lanes 0..31 into a 16-deep LDS ring, 8 steps ahead (reg-staged;
// bar_lds never drains vmcnt so the prefetch overlaps the chain).
// ---------------------------------------------------------------------------
__global__ __attribute__((amdgpu_waves_per_eu(1, 1)))
__launch_bounds__(256, 1) void k_recur12f(const float* __restrict__ seq_in,
                                          float* __restrict__ seq_out,
                                          const float* __restrict__ whpk,
                                          const float* __restrict__ wihpk,
                                          const float* __restrict__ bpk) {
  const int wg = blockIdx.x, dir = wg >> 6, b = wg & 63;
  const int tid4 = threadIdx.x;
  const int w4 = tid4 >> 6, l = tid4 & 63, u = l >> 2, q = l & 3;
  const int j = w4 * 16 + u;

  f32x2 w_if[16], w_go[16];
#pragma unroll
  for (int kl = 0; kl < 16; ++kl) {
    const f32x4 v = *reinterpret_cast<const f32x4*>(&whpk[(size_t)((dir * 16 + kl) * 256 + tid4) * 4]);
    w_if[kl] = __builtin_shufflevector(v, v, 0, 1);
    w_go[kl] = __builtin_shufflevector(v, v, 2, 3);
  }
  f32x2 wi_if[32], wi_go[32];
#pragma unroll
  for (int kl = 0; kl < 32; ++kl) {
    const f32x4 v = *reinterpret_cast<const f32x4*>(&wihpk[(size_t)((dir * 32 + kl) * 256 + tid4) * 4]);
    wi_if[kl] = __builtin_shufflevector(v, v, 0, 1);
    wi_go[kl] = __builtin_shufflevector(v, v, 2, 3);
  }
#pragma unroll
  for (int kl = 0; kl < 16; ++kl) { pinreg2(w_if[kl]); pinreg2(w_go[kl]); }
#pragma unroll
  for (int kl = 0; kl < 32; ++kl) { pinreg2(wi_if[kl]); pinreg2(wi_go[kl]); }
  f32x4 bv = *reinterpret_cast<const f32x4*>(&bpk[(size_t)(dir * 256 + tid4) * 4]);
  pinreg4(bv);

  __shared__ __align__(16) float h_lds[2][HID];
  __shared__ __align__(16) float ring[16][D2];
  if (tid4 < HID) h_lds[0][tid4] = 0.f;
  float c = 0.f;

  const int t0 = dir ? (T_LEN - 1) : 0;
  const int dt = dir ? -1 : 1;
  const bool stager = (w4 == 0) && (l < 32);

  float4 stage = {0.f, 0.f, 0.f, 0.f};
  if (stager) {
    // prologue: rows 0..7 -> ring, issue row-8 load into regs
    for (int p = 0; p < 8; ++p) {
      const int tt = t0 + dt * p;
      *reinterpret_cast<float4*>(&ring[p][l * 4]) =
          *reinterpret_cast<const float4*>(&seq_in[((size_t)tt * BATCH + b) * D2 + l * 4]);
    }
    const int tt8 = t0 + dt * 8;
    stage = *reinterpret_cast<const float4*>(&seq_in[((size_t)tt8 * BATCH + b) * D2 + l * 4]);
  }
  bar_lds();

  int t = t0;
  int par = 0;
  for (int it = 0; it < T_LEN; ++it) {
    // staging: commit row it+8 from regs, issue load for row it+9
    if (stager) {
      *reinterpret_cast<float4*>(&ring[(it + 8) & 15][l * 4]) = stage;
      int r = it + 9; if (r > T_LEN - 1) r = T_LEN - 1;
      const int tt = t0 + dt * r;
      stage = *reinterpret_cast<const float4*>(&seq_in[((size_t)tt * BATCH + b) * D2 + l * 4]);
    }
    const float* hbase = &h_lds[par][q * 16];
    const float* rrow = &ring[it & 15][0];

    f32x2 aif = {bv.x, bv.y}, ago = {bv.z, bv.w};
    f32x2 aif1 = {0.f, 0.f}, ago1 = {0.f, 0.f};
    // ih dot over this lane's 32 k's: chunks at m*16 + q*4 (bank-disjoint per q)
#pragma unroll
    for (int m = 0; m < 8; ++m) {
      const f32x4 hh = *reinterpret_cast<const f32x4*>(&rrow[m * 16 + q * 4]);
      const f32x2 ha = __builtin_shufflevector(hh, hh, 0, 1);
      const f32x2 hb = __builtin_shufflevector(hh, hh, 2, 3);
      pkfma_lo(aif,  ha, wi_if[4 * m + 0]); pkfma_lo(ago,  ha, wi_go[4 * m + 0]);
      pkfma_hi(aif1, ha, wi_if[4 * m + 1]); pkfma_hi(ago1, ha, wi_go[4 * m + 1]);
      pkfma_lo(aif,  hb, wi_if[4 * m + 2]); pkfma_lo(ago,  hb, wi_go[4 * m + 2]);
      pkfma_hi(aif1, hb, wi_if[4 * m + 3]); pkfma_hi(ago1, hb, wi_go[4 * m + 3]);
    }
    // hh dot
    dot16(hbase, w_if, w_go, aif, ago, aif1, ago1);
    aif += aif1; ago += ago1;

    const float pi = quad_sum(aif.x), pf = quad_sum(aif.y);
    const float pg = quad_sum(ago.x), po = quad_sum(ago.y);
    const float v = (q == 0) ? pi : ((q == 1) ? pf : ((q == 2) ? pg : po));
    const float hv = cell_update(v, q, c);

    if (q == 0) {
      h_lds[par ^ 1][j] = hv;
      seq_out[((size_t)t * BATCH + b) * D2 + dir * HID + j] = hv;
    }
    bar_lds();
    par ^= 1;
    t += dt;
  }
}

// ---------------------------------------------------------------------------
// Head MLP.
// ---------------------------------------------------------------------------
__global__ __launch_bounds__(128) void k_head(const float* __restrict__ seq,
                                              const float* __restrict__ Wc1, const float* __restrict__ bc1,
                                              const float* __restrict__ Wc2, const float* __restrict__ bc2,
                                              const float* __restrict__ Wc3, const float* __restrict__ bc3,
                                              float* __restrict__ out) {
  int b = blockIdx.x;
  int tid = threadIdx.x;
  __shared__ float fin[D2], z1[D2], z2[HID];
  if (tid < HID) fin[tid] = seq[((size_t)(T_LEN - 1) * BATCH + b) * D2 + tid];
  else           fin[tid] = seq[(size_t)b * D2 + tid];
  __syncthreads();
  float s = bc1[tid];
  for (int k = 0; k < D2; ++k) s = fmaf(fin[k], Wc1[(size_t)tid * D2 + k], s);
  z1[tid] = fmaxf(s, 0.f);
  __syncthreads();
  if (tid < HID) {
    float s2 = bc2[tid];
    for (int k = 0; k < D2; ++k) s2 = fmaf(z1[k], Wc2[(size_t)tid * D2 + k], s2);
    z2[tid] = fmaxf(s2, 0.f);
  }
  __syncthreads();
  if (tid < 20) {
    float s3 = bc3[tid];
    for (int k = 0; k < HID; ++k) s3 = fmaf(z2[k], Wc3[(size_t)tid * HID + k], s3);
    out[b * 20 + tid] = s3;
  }
}

// ---------------------------------------------------------------------------
#define WHPK0_F   (2*16*256*4)
#define WHPK12_F  (4*16*256*4)
#define WIHPK12_F (4*32*256*4)
#define B12PK_F   (4*256*4)
#define W0PK_F    (2*3*256*4)
#define B0PK_F    (2*256*4)

extern "C" void kernel_launch(void* const* d_in, const int* in_sizes, int n_in,
                              void* d_out, int out_size, void* d_ws, size_t ws_size,
                              hipStream_t stream) {
  const float* x      = (const float*)d_in[0];
  const float* Wp     = (const float*)d_in[1];
  const float* bp     = (const float*)d_in[2];
  const float* w_ih0  = (const float*)d_in[3];
  const float* w_hh0  = (const float*)d_in[4];
  const float* b_ih0  = (const float*)d_in[5];
  const float* b_hh0  = (const float*)d_in[6];
  const float* w_ih12 = (const float*)d_in[7];
  const float* w_hh12 = (const float*)d_in[8];
  const float* b_ih12 = (const float*)d_in[9];
  const float* b_hh12 = (const float*)d_in[10];
  const float* Wc1    = (const float*)d_in[11];
  const float* bc1    = (const float*)d_in[12];
  const float* Wc2    = (const float*)d_in[13];
  const float* bc2    = (const float*)d_in[14];
  const float* Wc3    = (const float*)d_in[15];
  const float* bc3    = (const float*)d_in[16];
  float* out = (float*)d_out;
  float* ws  = (float*)d_ws;

  const size_t SEQ = (size_t)NROW * D2;   // 20,480,000 floats
  float* seqA    = ws;
  float* seqB    = seqA + SEQ;
  float* whpk0   = seqB + SEQ;
  float* whpk12  = whpk0 + WHPK0_F;
  float* wihpk12 = whpk12 + WHPK12_F;
  float* b12pk   = wihpk12 + WIHPK12_F;
  float* w0pk    = b12pk + B12PK_F;
  float* b0pk    = w0pk + W0PK_F;

  hipLaunchKernelGGL(k_prep, dim3(2), dim3(256), 0, stream,
                     Wp, bp, w_ih0, w_hh0, b_ih0, b_hh0, w_ih12, w_hh12, b_ih12, b_hh12,
                     whpk0, whpk12, wihpk12, b12pk, w0pk, b0pk);
  hipLaunchKernelGGL(k_recur0, dim3(128), dim3(256), 0, stream, x, w0pk, b0pk, whpk0, seqA);

  // layer 1: seqA -> seqB ; layer 2: seqB -> seqA
  hipLaunchKernelGGL(k_recur12f, dim3(128), dim3(256), 0, stream,
                     seqA, seqB,
                     whpk12  + (size_t)0 * 2 * 16 * 256 * 4,
                     wihpk12 + (size_t)0 * 2 * 32 * 256 * 4,
                     b12pk   + (size_t)0 * 2 * 256 * 4);
  hipLaunchKernelGGL(k_recur12f, dim3(128), dim3(256), 0, stream,
                     seqB, seqA,
                     whpk12  + (size_t)1 * 2 * 16 * 256 * 4,
                     wihpk12 + (size_t)1 * 2 * 32 * 256 * 4,
                     b12pk   + (size_t)1 * 2 * 256 * 4);

  hipLaunchKernelGGL(k_head, dim3(BATCH), dim3(128), 0, stream,
                     seqA, Wc1, bc1, Wc2, bc2, Wc3, bc3, out);
}